// Round 1
// baseline (173.122 us; speedup 1.0000x reference)
//
#include <hip/hip_runtime.h>

#define NTOK 64
#define HEADS 8

typedef __attribute__((ext_vector_type(4))) float f32x4;
typedef __attribute__((ext_vector_type(8))) short bf16x8;

__device__ __forceinline__ unsigned short f2bf(float f) {
    unsigned int u = __float_as_uint(f);
    u += 0x7FFFu + ((u >> 16) & 1u);   // round-to-nearest-even bf16
    return (unsigned short)(u >> 16);
}

// bias_ws layout: [h][nt][mt][lane][r] (float) = log2(e) * bias[h][n][m]
// with n = nt*16 + (lane>>4)*4 + r, m = mt*16 + (lane&15)  (MFMA C/D layout)
__global__ void bias_mlp_kernel(const float* __restrict__ w1,
                                const float* __restrict__ b1,
                                const float* __restrict__ w2,
                                const float* __restrict__ b2,
                                float* __restrict__ bias_ws)
{
    int idx = blockIdx.x * 256 + threadIdx.x;   // 32768 total
    int r  = idx & 3;
    int l  = (idx >> 2) & 63;
    int mt = (idx >> 8) & 3;
    int nt = (idx >> 10) & 3;
    int h  = (idx >> 12);                       // wave-uniform -> scalar loads
    int n = nt * 16 + (l >> 4) * 4 + r;
    int m = mt * 16 + (l & 15);
    float dy = (float)((n >> 3) - (m >> 3));
    float dx = (float)((n & 7) - (m & 7));
    float fy = copysignf(log1pf(fabsf(dy)), dy);
    float fx = copysignf(log1pf(fabsf(dx)), dx);
    float acc = 0.0f;
    for (int j = 0; j < 256; ++j) {
        float t = fy * w1[j] + fx * w1[256 + j] + b1[j];
        float ge = 0.5f * t * (1.0f + erff(t * 0.70710678118654752f)); // exact GELU
        acc = fmaf(ge, w2[j * HEADS + h], acc);
    }
    bias_ws[idx] = (acc + b2[h]) * 1.44269504088896341f;  // fold log2(e)
}

// One wave per (window b, head h). 4 waves / block, independent.
__global__ __launch_bounds__(256) void win_attn_kernel(
    const float* __restrict__ qkv,
    const float* __restrict__ bias_ws,
    float* __restrict__ out)
{
    __shared__ __align__(16) unsigned short p_lds[4][NTOK][72]; // 72-elem stride: 144B rows, 16B-aligned
    const int w = threadIdx.x >> 6;
    const int l = threadIdx.x & 63;
    const int c = l & 15;
    const int g = l >> 4;
    const int W = blockIdx.x * 4 + w;
    const int h = W & 7;
    const int b = W >> 3;
    const float* base = qkv + (size_t)b * (NTOK * 768) + h * 32;
    const float QS = 0.176776695296636893f * 1.44269504088896341f; // scale * log2(e)

    // ---- Q,K fragments straight from global (A/B frag layout: i/col = lane&15, k-chunk = (lane>>4)*8) ----
    bf16x8 qf[4], kf[4];
    #pragma unroll
    for (int t = 0; t < 4; ++t) {
        const float* pq = base + (size_t)(t * 16 + c) * 768 + g * 8;
        f32x4 x0 = *(const f32x4*)(pq);
        f32x4 x1 = *(const f32x4*)(pq + 4);
        f32x4 y0 = *(const f32x4*)(pq + 256);
        f32x4 y1 = *(const f32x4*)(pq + 260);
        bf16x8 q, k;
        #pragma unroll
        for (int j = 0; j < 4; ++j) {
            q[j]     = (short)f2bf(x0[j] * QS);
            q[4 + j] = (short)f2bf(x1[j] * QS);
            k[j]     = (short)f2bf(y0[j]);
            k[4 + j] = (short)f2bf(y1[j]);
        }
        qf[t] = q;
        kf[t] = k;
    }

    // ---- S = log2e*(scale*Q.K^T + bias): seed accumulators with precomputed bias frags ----
    f32x4 acc[4][4];
    {
        const f32x4* bw = (const f32x4*)(bias_ws) + (size_t)h * 1024 + l;
        #pragma unroll
        for (int nt = 0; nt < 4; ++nt)
            #pragma unroll
            for (int mt = 0; mt < 4; ++mt)
                acc[nt][mt] = bw[(nt * 4 + mt) * 64];
    }
    #pragma unroll
    for (int nt = 0; nt < 4; ++nt)
        #pragma unroll
        for (int mt = 0; mt < 4; ++mt)
            acc[nt][mt] = __builtin_amdgcn_mfma_f32_16x16x32_bf16(qf[nt], kf[mt], acc[nt][mt], 0, 0, 0);

    // ---- V fragments (B layout) loaded early to hide latency under softmax ----
    bf16x8 vf[2][2];
    {
        const float* vb = base + 512;
        #pragma unroll
        for (int ks = 0; ks < 2; ++ks)
            #pragma unroll
            for (int dt = 0; dt < 2; ++dt) {
                bf16x8 v;
                #pragma unroll
                for (int j = 0; j < 8; ++j)
                    v[j] = (short)f2bf(vb[(size_t)(ks * 32 + g * 8 + j) * 768 + dt * 16 + c]);
                vf[ks][dt] = v;
            }
    }

    // ---- row softmax: rows (nt, g, r); cols spread over 4 mt regs x 16 c-lanes ----
    float sm[4][4];
    #pragma unroll
    for (int nt = 0; nt < 4; ++nt) {
        #pragma unroll
        for (int r = 0; r < 4; ++r) {
            float a = fmaxf(fmaxf(acc[nt][0][r], acc[nt][1][r]),
                            fmaxf(acc[nt][2][r], acc[nt][3][r]));
            a = fmaxf(a, __shfl_xor(a, 1, 64));
            a = fmaxf(a, __shfl_xor(a, 2, 64));
            a = fmaxf(a, __shfl_xor(a, 4, 64));
            a = fmaxf(a, __shfl_xor(a, 8, 64));
            float s = 0.0f;
            #pragma unroll
            for (int mt = 0; mt < 4; ++mt) {
                float p = exp2f(acc[nt][mt][r] - a);   // acc already in log2 units
                acc[nt][mt][r] = p;
                s += p;
            }
            s += __shfl_xor(s, 1, 64);
            s += __shfl_xor(s, 2, 64);
            s += __shfl_xor(s, 4, 64);
            s += __shfl_xor(s, 8, 64);
            sm[nt][r] = s;
        }
    }

    // ---- P (bf16) -> LDS bounce to re-layout C-frags into A-frags ----
    unsigned short (*P)[72] = p_lds[w];
    #pragma unroll
    for (int nt = 0; nt < 4; ++nt)
        #pragma unroll
        for (int mt = 0; mt < 4; ++mt)
            #pragma unroll
            for (int r = 0; r < 4; ++r)
                P[nt * 16 + g * 4 + r][mt * 16 + c] = f2bf(acc[nt][mt][r]);
    __syncthreads();

    // ---- O = P.V ----
    f32x4 o[4][2];
    #pragma unroll
    for (int nt = 0; nt < 4; ++nt)
        #pragma unroll
        for (int dt = 0; dt < 2; ++dt)
            o[nt][dt] = (f32x4){0.f, 0.f, 0.f, 0.f};
    #pragma unroll
    for (int nt = 0; nt < 4; ++nt)
        #pragma unroll
        for (int ks = 0; ks < 2; ++ks) {
            bf16x8 pa = *(const bf16x8*)(&P[nt * 16 + c][ks * 32 + g * 8]); // 16B aligned
            #pragma unroll
            for (int dt = 0; dt < 2; ++dt)
                o[nt][dt] = __builtin_amdgcn_mfma_f32_16x16x32_bf16(pa, vf[ks][dt], o[nt][dt], 0, 0, 0);
        }

    // ---- normalize rows by softmax denom, store ----
    float* ob = out + (size_t)b * (NTOK * 256) + h * 32;
    #pragma unroll
    for (int nt = 0; nt < 4; ++nt) {
        #pragma unroll
        for (int r = 0; r < 4; ++r) {
            float inv = __builtin_amdgcn_rcpf(sm[nt][r]);
            #pragma unroll
            for (int dt = 0; dt < 2; ++dt)
                ob[(size_t)(nt * 16 + g * 4 + r) * 256 + dt * 16 + c] = o[nt][dt][r] * inv;
        }
    }
}

extern "C" void kernel_launch(void* const* d_in, const int* in_sizes, int n_in,
                              void* d_out, int out_size, void* d_ws, size_t ws_size,
                              hipStream_t stream) {
    const float* qkv = (const float*)d_in[0];
    const float* w1  = (const float*)d_in[1];
    const float* b1  = (const float*)d_in[2];
    const float* w2  = (const float*)d_in[3];
    const float* b2  = (const float*)d_in[4];
    float* bias_ws = (float*)d_ws;   // 32768 floats = 128 KiB

    bias_mlp_kernel<<<128, 256, 0, stream>>>(w1, b1, w2, b2, bias_ws);

    int B = in_sizes[0] / (NTOK * 768 * 3 / 3);   // = in_sizes[0] / 49152
    win_attn_kernel<<<B * 2, 256, 0, stream>>>(qkv, bias_ws, (float*)d_out);
}

// Round 2
// 162.884 us; speedup vs baseline: 1.0629x; 1.0629x over previous
//
#include <hip/hip_runtime.h>

#define NTOK 64
#define HEADS 8

typedef __attribute__((ext_vector_type(4))) float f32x4;
typedef __attribute__((ext_vector_type(2))) unsigned int u32x2;
typedef __attribute__((ext_vector_type(8))) short bf16x8;

__device__ __forceinline__ unsigned int f2bf(float f) {
    unsigned int u = __float_as_uint(f);
    u += 0x7FFFu + ((u >> 16) & 1u);   // round-to-nearest-even bf16
    return u >> 16;
}

// bias_ws layout: [h][mt][nt][lane][r] (float) = log2(e) * bias[h][n][m]
// with m = mt*16 + (lane>>4)*4 + r (S^T C-frag row), n = nt*16 + (lane&15) (col)
__global__ void bias_mlp_kernel(const float* __restrict__ w1,
                                const float* __restrict__ b1,
                                const float* __restrict__ w2,
                                const float* __restrict__ b2,
                                float* __restrict__ bias_ws)
{
    int idx = blockIdx.x * 256 + threadIdx.x;   // 32768 total
    int r  = idx & 3;
    int l  = (idx >> 2) & 63;
    int nt = (idx >> 8) & 3;
    int mt = (idx >> 10) & 3;
    int h  = (idx >> 12);                       // wave-uniform -> scalar loads
    int n = nt * 16 + (l & 15);
    int m = mt * 16 + (l >> 4) * 4 + r;
    float dy = (float)((n >> 3) - (m >> 3));
    float dx = (float)((n & 7) - (m & 7));
    float fy = copysignf(log1pf(fabsf(dy)), dy);
    float fx = copysignf(log1pf(fabsf(dx)), dx);
    float acc = 0.0f;
    for (int j = 0; j < 256; ++j) {
        float t = fy * w1[j] + fx * w1[256 + j] + b1[j];
        float ge = 0.5f * t * (1.0f + erff(t * 0.70710678118654752f)); // exact GELU
        acc = fmaf(ge, w2[j * HEADS + h], acc);
    }
    bias_ws[idx] = (acc + b2[h]) * 1.44269504088896341f;  // fold log2(e)
}

// One wave per (window b, head h). 4 waves / block, fully independent (no barrier).
__global__ __launch_bounds__(256) void win_attn_kernel(
    const float* __restrict__ qkv,
    const float* __restrict__ bias_ws,
    float* __restrict__ out)
{
    __shared__ __align__(16) unsigned short p_lds[4][NTOK][72]; // wave-private slices
    const int w = threadIdx.x >> 6;
    const int l = threadIdx.x & 63;
    const int c = l & 15;
    const int g = l >> 4;
    const int W = blockIdx.x * 4 + w;
    const int h = W & 7;
    const int b = W >> 3;
    const float* base = qkv + (size_t)b * (NTOK * 768) + h * 32;
    const float QS = 0.176776695296636893f * 1.44269504088896341f; // scale * log2(e)

    // ---- Q,K fragments straight from global (frag layout: own-row = lane&15, k-chunk = (lane>>4)*8) ----
    bf16x8 qf[4], kf[4];
    #pragma unroll
    for (int t = 0; t < 4; ++t) {
        const float* pq = base + (size_t)(t * 16 + c) * 768 + g * 8;
        f32x4 x0 = *(const f32x4*)(pq);
        f32x4 x1 = *(const f32x4*)(pq + 4);
        f32x4 y0 = *(const f32x4*)(pq + 256);
        f32x4 y1 = *(const f32x4*)(pq + 260);
        bf16x8 q, k;
        #pragma unroll
        for (int j = 0; j < 4; ++j) {
            q[j]     = (short)f2bf(x0[j] * QS);
            q[4 + j] = (short)f2bf(x1[j] * QS);
            k[j]     = (short)f2bf(y0[j]);
            k[4 + j] = (short)f2bf(y1[j]);
        }
        qf[t] = q;
        kf[t] = k;
    }

    // ---- V^T A-fragments (lane: d = dt*16+c, k = m = ks*32 + g*8 + j), issued early ----
    bf16x8 vf[2][2];
    {
        const float* vb = base + 512;
        #pragma unroll
        for (int ks = 0; ks < 2; ++ks)
            #pragma unroll
            for (int dt = 0; dt < 2; ++dt) {
                bf16x8 v;
                #pragma unroll
                for (int j = 0; j < 8; ++j)
                    v[j] = (short)f2bf(vb[(size_t)(ks * 32 + g * 8 + j) * 768 + dt * 16 + c]);
                vf[ks][dt] = v;
            }
    }

    // ---- S^T = log2e*(scale*K.Q^T + bias^T): acc[mt][nt], m = mt*16+g*4+r, n = nt*16+c ----
    f32x4 acc[4][4];
    {
        const f32x4* bw = (const f32x4*)(bias_ws) + (size_t)h * 1024 + l;
        #pragma unroll
        for (int mt = 0; mt < 4; ++mt)
            #pragma unroll
            for (int nt = 0; nt < 4; ++nt)
                acc[mt][nt] = bw[(mt * 4 + nt) * 64];
    }
    #pragma unroll
    for (int mt = 0; mt < 4; ++mt)
        #pragma unroll
        for (int nt = 0; nt < 4; ++nt)
            acc[mt][nt] = __builtin_amdgcn_mfma_f32_16x16x32_bf16(kf[mt], qf[nt], acc[mt][nt], 0, 0, 0);

    // ---- softmax over m for each n=nt*16+c: 16 values in-lane + xor16/xor32 across g ----
    float sm[4];
    #pragma unroll
    for (int nt = 0; nt < 4; ++nt) {
        float mx = acc[0][nt][0];
        #pragma unroll
        for (int mt = 0; mt < 4; ++mt)
            #pragma unroll
            for (int r = 0; r < 4; ++r)
                mx = fmaxf(mx, acc[mt][nt][r]);
        mx = fmaxf(mx, __shfl_xor(mx, 16, 64));
        mx = fmaxf(mx, __shfl_xor(mx, 32, 64));
        float s = 0.0f;
        #pragma unroll
        for (int mt = 0; mt < 4; ++mt)
            #pragma unroll
            for (int r = 0; r < 4; ++r) {
                float p = exp2f(acc[mt][nt][r] - mx);   // already in log2 units
                acc[mt][nt][r] = p;
                s += p;
            }
        s += __shfl_xor(s, 16, 64);
        s += __shfl_xor(s, 32, 64);
        sm[nt] = s;
    }

    // ---- P (bf16, [n][m] layout) -> LDS via packed b64 writes (4 consecutive m per reg) ----
    unsigned short (*P)[72] = p_lds[w];
    #pragma unroll
    for (int nt = 0; nt < 4; ++nt)
        #pragma unroll
        for (int mt = 0; mt < 4; ++mt) {
            unsigned int w0 = f2bf(acc[mt][nt][0]) | (f2bf(acc[mt][nt][1]) << 16);
            unsigned int w1 = f2bf(acc[mt][nt][2]) | (f2bf(acc[mt][nt][3]) << 16);
            *(u32x2*)(&P[nt * 16 + c][mt * 16 + g * 4]) = (u32x2){w0, w1};
        }

    // ---- O^T = V^T . P^T : A = V^T frag, B = P frag (ds_read_b128, 16B aligned) ----
    f32x4 o[4][2];
    #pragma unroll
    for (int nt = 0; nt < 4; ++nt)
        #pragma unroll
        for (int dt = 0; dt < 2; ++dt)
            o[nt][dt] = (f32x4){0.f, 0.f, 0.f, 0.f};
    #pragma unroll
    for (int nt = 0; nt < 4; ++nt)
        #pragma unroll
        for (int ks = 0; ks < 2; ++ks) {
            bf16x8 pb = *(const bf16x8*)(&P[nt * 16 + c][ks * 32 + g * 8]);
            #pragma unroll
            for (int dt = 0; dt < 2; ++dt)
                o[nt][dt] = __builtin_amdgcn_mfma_f32_16x16x32_bf16(vf[ks][dt], pb, o[nt][dt], 0, 0, 0);
        }

    // ---- normalize by denom (in-lane per n) and store as f32x4 (4 consecutive d per reg) ----
    float* ob = out + (size_t)b * (NTOK * 256) + h * 32;
    #pragma unroll
    for (int nt = 0; nt < 4; ++nt) {
        float iv = __builtin_amdgcn_rcpf(sm[nt]);
        #pragma unroll
        for (int dt = 0; dt < 2; ++dt) {
            f32x4 val;
            #pragma unroll
            for (int r = 0; r < 4; ++r)
                val[r] = o[nt][dt][r] * iv;
            *(f32x4*)(ob + (size_t)(nt * 16 + c) * 256 + dt * 16 + g * 4) = val;
        }
    }
}

extern "C" void kernel_launch(void* const* d_in, const int* in_sizes, int n_in,
                              void* d_out, int out_size, void* d_ws, size_t ws_size,
                              hipStream_t stream) {
    const float* qkv = (const float*)d_in[0];
    const float* w1  = (const float*)d_in[1];
    const float* b1  = (const float*)d_in[2];
    const float* w2  = (const float*)d_in[3];
    const float* b2  = (const float*)d_in[4];
    float* bias_ws = (float*)d_ws;   // 32768 floats = 128 KiB

    bias_mlp_kernel<<<128, 256, 0, stream>>>(w1, b1, w2, b2, bias_ws);

    int B = in_sizes[0] / 49152;   // windows
    win_attn_kernel<<<B * 2, 256, 0, stream>>>(qkv, bias_ws, (float*)d_out);
}

// Round 3
// 139.754 us; speedup vs baseline: 1.2388x; 1.1655x over previous
//
#include <hip/hip_runtime.h>

#define NTOK 64
#define HEADS 8

typedef __attribute__((ext_vector_type(4))) float f32x4;
typedef __attribute__((ext_vector_type(2))) unsigned int u32x2;
typedef __attribute__((ext_vector_type(8))) short bf16x8;

__device__ float g_bias225[225 * 8];   // overwritten fully every launch (deterministic)

__device__ __forceinline__ unsigned int f2bf(float f) {
    unsigned int u = __float_as_uint(f);
    u += 0x7FFFu + ((u >> 16) & 1u);   // round-to-nearest-even bf16
    return u >> 16;
}

// Stage 1: MLP over the 225 distinct relative positions. One wave per pair.
// lane: h = lane&7, j-subset = (lane>>3) + 8*i  (GELU recomputed 8x per j -- trivial)
__global__ __launch_bounds__(64) void mlp_pairs_kernel(
    const float* __restrict__ w1, const float* __restrict__ b1,
    const float* __restrict__ w2, const float* __restrict__ b2)
{
    int pair = blockIdx.x;
    int lane = threadIdx.x;
    int dy = pair / 15 - 7;
    int dx = pair % 15 - 7;
    float fy = copysignf(log1pf(fabsf((float)dy)), (float)dy);
    float fx = copysignf(log1pf(fabsf((float)dx)), (float)dx);
    int h = lane & 7;
    int j0 = lane >> 3;
    float acc = 0.0f;
    #pragma unroll 4
    for (int i = 0; i < 32; ++i) {
        int j = j0 + 8 * i;
        float t = fy * w1[j] + fx * w1[256 + j] + b1[j];
        float ge = 0.5f * t * (1.0f + erff(t * 0.70710678118654752f)); // exact GELU
        acc = fmaf(ge, w2[j * HEADS + h], acc);
    }
    acc += __shfl_xor(acc, 8, 64);
    acc += __shfl_xor(acc, 16, 64);
    acc += __shfl_xor(acc, 32, 64);
    if (lane < 8)
        g_bias225[pair * 8 + lane] = (acc + b2[lane]) * 1.44269504088896341f; // fold log2(e)
}

// Stage 2: scatter bias225 -> fragment-layout table
// bias_ws[h][mt][nt][lane][r] = log2e * bias[h][n][m],
//   m = mt*16 + (lane>>4)*4 + r (S^T C-frag row), n = nt*16 + (lane&15) (col)
__global__ __launch_bounds__(256) void bias_scatter_kernel(float* __restrict__ bias_ws)
{
    int idx = blockIdx.x * 256 + threadIdx.x;   // 32768 total
    int r  = idx & 3;
    int l  = (idx >> 2) & 63;
    int nt = (idx >> 8) & 3;
    int mt = (idx >> 10) & 3;
    int h  = idx >> 12;
    int n = nt * 16 + (l & 15);
    int m = mt * 16 + (l >> 4) * 4 + r;
    int pair = ((n >> 3) - (m >> 3) + 7) * 15 + ((n & 7) - (m & 7) + 7);
    bias_ws[idx] = g_bias225[pair * 8 + h];
}

// One wave per (window b, head h). 4 waves/block, fully independent (no barrier).
// nt quarter-split to cut VGPR pressure -> higher occupancy -> more HBM MLP.
__global__ __launch_bounds__(256) void win_attn_kernel(
    const float* __restrict__ qkv,
    const float* __restrict__ bias_ws,
    float* __restrict__ out)
{
    __shared__ __align__(16) unsigned short p_lds[4][16][72]; // 9216 B, wave-private slices
    const int w = threadIdx.x >> 6;
    const int l = threadIdx.x & 63;
    const int c = l & 15;
    const int g = l >> 4;
    const int W = blockIdx.x * 4 + w;
    const int h = W & 7;
    const int b = W >> 3;
    const float* base = qkv + (size_t)b * (NTOK * 768) + h * 32;
    const float QS = 0.176776695296636893f * 1.44269504088896341f; // scale * log2(e)

    // ---- K fragments (A-frag: own-row m-tile = lane&15, k-chunk = g*8) ----
    bf16x8 kf[4];
    #pragma unroll
    for (int t = 0; t < 4; ++t) {
        const float* pk = base + (size_t)(t * 16 + c) * 768 + 256 + g * 8;
        f32x4 y0 = *(const f32x4*)(pk);
        f32x4 y1 = *(const f32x4*)(pk + 4);
        bf16x8 k;
        #pragma unroll
        for (int j = 0; j < 4; ++j) {
            k[j]     = (short)f2bf(y0[j]);
            k[4 + j] = (short)f2bf(y1[j]);
        }
        kf[t] = k;
    }

    // ---- V^T A-fragments (lane: d = dt*16+c, k = m = ks*32 + g*8 + j) ----
    bf16x8 vf[2][2];
    {
        const float* vb = base + 512;
        #pragma unroll
        for (int ks = 0; ks < 2; ++ks)
            #pragma unroll
            for (int dt = 0; dt < 2; ++dt) {
                bf16x8 v;
                #pragma unroll
                for (int j = 0; j < 8; ++j)
                    v[j] = (short)f2bf(vb[(size_t)(ks * 32 + g * 8 + j) * 768 + dt * 16 + c]);
                vf[ks][dt] = v;
            }
    }

    unsigned short (*P)[72] = p_lds[w];
    float* ob = out + (size_t)b * (NTOK * 256) + h * 32;

    // ---- quarter loop over n-strips (nt): S^T strip -> softmax -> P -> O^T strip ----
    #pragma unroll
    for (int nt = 0; nt < 4; ++nt) {
        // Q strip fragment (B-frag: own-col n = lane&15, k-chunk g*8)
        bf16x8 qf;
        {
            const float* pq = base + (size_t)(nt * 16 + c) * 768 + g * 8;
            f32x4 x0 = *(const f32x4*)(pq);
            f32x4 x1 = *(const f32x4*)(pq + 4);
            #pragma unroll
            for (int j = 0; j < 4; ++j) {
                qf[j]     = (short)f2bf(x0[j] * QS);
                qf[4 + j] = (short)f2bf(x1[j] * QS);
            }
        }

        // seed with bias frags, S^T strip = K.Q^T + bias
        f32x4 acc[4];
        {
            const f32x4* bw = (const f32x4*)(bias_ws) + ((size_t)h * 16 + nt) * 64 + l;
            #pragma unroll
            for (int mt = 0; mt < 4; ++mt)
                acc[mt] = bw[mt * 256];
        }
        #pragma unroll
        for (int mt = 0; mt < 4; ++mt)
            acc[mt] = __builtin_amdgcn_mfma_f32_16x16x32_bf16(kf[mt], qf, acc[mt], 0, 0, 0);

        // softmax over m for n = nt*16+c: 16 in-lane + xor16/xor32 across g
        float mx = acc[0][0];
        #pragma unroll
        for (int mt = 0; mt < 4; ++mt)
            #pragma unroll
            for (int r = 0; r < 4; ++r)
                mx = fmaxf(mx, acc[mt][r]);
        mx = fmaxf(mx, __shfl_xor(mx, 16, 64));
        mx = fmaxf(mx, __shfl_xor(mx, 32, 64));
        float s = 0.0f;
        #pragma unroll
        for (int mt = 0; mt < 4; ++mt)
            #pragma unroll
            for (int r = 0; r < 4; ++r) {
                float p = exp2f(acc[mt][r] - mx);   // already in log2 units
                acc[mt][r] = p;
                s += p;
            }
        s += __shfl_xor(s, 16, 64);
        s += __shfl_xor(s, 32, 64);
        float iv = __builtin_amdgcn_rcpf(s);

        // P strip (bf16, [n][m]) -> LDS (packed b64 writes; wave-serial reuse, no barrier)
        #pragma unroll
        for (int mt = 0; mt < 4; ++mt) {
            unsigned int w0 = f2bf(acc[mt][0]) | (f2bf(acc[mt][1]) << 16);
            unsigned int w1 = f2bf(acc[mt][2]) | (f2bf(acc[mt][3]) << 16);
            *(u32x2*)(&P[c][mt * 16 + g * 4]) = (u32x2){w0, w1};
        }

        // O^T strip = V^T . P^T
        f32x4 o[2];
        o[0] = (f32x4){0.f, 0.f, 0.f, 0.f};
        o[1] = (f32x4){0.f, 0.f, 0.f, 0.f};
        #pragma unroll
        for (int ks = 0; ks < 2; ++ks) {
            bf16x8 pb = *(const bf16x8*)(&P[c][ks * 32 + g * 8]);
            #pragma unroll
            for (int dt = 0; dt < 2; ++dt)
                o[dt] = __builtin_amdgcn_mfma_f32_16x16x32_bf16(vf[ks][dt], pb, o[dt], 0, 0, 0);
        }

        // normalize + store (4 consecutive d per reg -> dwordx4)
        #pragma unroll
        for (int dt = 0; dt < 2; ++dt) {
            f32x4 val;
            #pragma unroll
            for (int r = 0; r < 4; ++r)
                val[r] = o[dt][r] * iv;
            *(f32x4*)(ob + (size_t)(nt * 16 + c) * 256 + dt * 16 + g * 4) = val;
        }
    }
}

extern "C" void kernel_launch(void* const* d_in, const int* in_sizes, int n_in,
                              void* d_out, int out_size, void* d_ws, size_t ws_size,
                              hipStream_t stream) {
    const float* qkv = (const float*)d_in[0];
    const float* w1  = (const float*)d_in[1];
    const float* b1  = (const float*)d_in[2];
    const float* w2  = (const float*)d_in[3];
    const float* b2  = (const float*)d_in[4];
    float* bias_ws = (float*)d_ws;   // 32768 floats = 128 KiB (proven size)

    mlp_pairs_kernel<<<225, 64, 0, stream>>>(w1, b1, w2, b2);
    bias_scatter_kernel<<<128, 256, 0, stream>>>(bias_ws);

    int B = in_sizes[0] / 49152;   // windows
    win_attn_kernel<<<B * 2, 256, 0, stream>>>(qkv, bias_ws, (float*)d_out);
}